// Round 1
// baseline (926.082 us; speedup 1.0000x reference)
//
#include <hip/hip_runtime.h>
#include <math.h>

#define NB 20
#define SDIM 160   // 20*8
#define H1 64
#define TWO_PI_F 6.28318530717958647692f

// ws layout (floats)
#define WS_FQW   0      // [64][24]
#define WS_COLW  1536   // [64][24]
#define WS_FQB   3072   // [64] effective bias (b + summary part)
#define WS_COLB  3136   // [64]
#define WS_COLWD 3200   // [64] col_w1[j][56] (density weight)
#define WS_FQW2  3264   // [64]
#define WS_COLW2 3328   // [3][64]
#define WS_MISC  3520   // [0]=fq_b2, [1..3]=col_b2

__device__ __forceinline__ float fast_sigmoid(float x){ return 1.0f/(1.0f+__expf(-x)); }
__device__ __forceinline__ float fast_softplus(float x){
    return fmaxf(x, 0.0f) + __logf(1.0f + __expf(-fabsf(x)));
}

__global__ __launch_bounds__(256) void blob_sim_kernel(
    const float* __restrict__ initial_state,
    const float* __restrict__ dyn_w1, const float* __restrict__ dyn_b1,
    const float* __restrict__ dyn_w2, const float* __restrict__ dyn_b2,
    const float* __restrict__ couplingP, const float* __restrict__ dampingP,
    const float* __restrict__ interaction,
    const float* __restrict__ summ_w, const float* __restrict__ summ_b,
    const float* __restrict__ fq_w1, const float* __restrict__ fq_b1,
    const float* __restrict__ fq_w2, const float* __restrict__ fq_b2,
    const float* __restrict__ col_w1, const float* __restrict__ col_b1,
    const float* __restrict__ col_w2, const float* __restrict__ col_b2,
    const int* __restrict__ tP,
    float* __restrict__ ws)
{
    __shared__ float sW1[SDIM*H1];   // transposed: sW1[k*H1+j] = dyn_w1[j*SDIM+k]
    __shared__ float sW2[H1*SDIM];   // transposed: sW2[k*SDIM+o] = dyn_w2[o*H1+k]
    __shared__ float sB1[H1];
    __shared__ float sB2[SDIM];
    __shared__ float sInter[NB*NB];
    __shared__ float sStA[SDIM];
    __shared__ float sStB[SDIM];
    __shared__ float sH[H1];
    __shared__ float sDn[SDIM];
    __shared__ float sPart[4*H1];
    __shared__ float sSum[32];

    const int t = threadIdx.x;

    for (int idx = t; idx < SDIM*H1; idx += 256){
        int j = idx / SDIM, k = idx % SDIM;
        sW1[k*H1 + j] = dyn_w1[idx];
    }
    for (int idx = t; idx < H1*SDIM; idx += 256){
        int o = idx / H1, k = idx % H1;
        sW2[k*SDIM + o] = dyn_w2[idx];
    }
    if (t < H1)   sB1[t] = dyn_b1[t];
    if (t < SDIM) sB2[t] = dyn_b2[t];
    for (int idx = t; idx < NB*NB; idx += 256) sInter[idx] = interaction[idx];
    if (t < SDIM) sStA[t] = initial_state[t];

    const float coupling = couplingP[0];
    const float damping  = dampingP[0];
    const int tv = tP[0];
    int n_steps = (int)((double)tv / 0.01);   // replicates Python int(t/DT): 2 -> 199
    if (n_steps < 1) n_steps = 1;
    const float adt = (float)((double)tv / (double)n_steps);
    __syncthreads();

    float* cur = sStA;
    float* nxt = sStB;
    const int j = t & 63;
    const int part = t >> 6;

    for (int step = 0; step < n_steps; ++step){
        // phase 1: partial dot for h = tanh(W1 @ flat + b1); thread (j, part)
        float acc = 0.0f;
        #pragma unroll
        for (int k = 0; k < 40; ++k){
            int kk = part*40 + k;
            acc = fmaf(cur[kk], sW1[kk*H1 + j], acc);
        }
        sPart[part*H1 + j] = acc;
        __syncthreads();
        if (t < H1){
            float v = sPart[t] + sPart[H1+t] + sPart[2*H1+t] + sPart[3*H1+t] + sB1[t];
            sH[t] = tanhf(v);
        }
        __syncthreads();
        // phase 2: dneural = W2 @ h + b2
        if (t < SDIM){
            float a = sB2[t];
            #pragma unroll
            for (int k = 0; k < H1; ++k) a = fmaf(sH[k], sW2[k*SDIM + t], a);
            sDn[t] = a;
        }
        __syncthreads();
        // phase 3: forces + state update -> nxt
        if (t < NB){
            const float px = cur[t*8+0], py = cur[t*8+1], pz = cur[t*8+2];
            const float vx = cur[t*8+3], vy = cur[t*8+4], vz = cur[t*8+5];
            const float sz = cur[t*8+6], in_ = cur[t*8+7];
            float fx = 0.f, fy = 0.f, fz = 0.f;
            #pragma unroll
            for (int jj = 0; jj < NB; ++jj){
                float dx = px - cur[jj*8+0];
                float dy = py - cur[jj*8+1];
                float dz = pz - cur[jj*8+2];
                float d  = sqrtf(dx*dx + dy*dy + dz*dz + 1e-6f);
                float mag = sInter[t*NB + jj] / (d*d + 1.0f);
                float w   = mag / (d + 1e-6f);
                fx = fmaf(dx, w, fx);
                fy = fmaf(dy, w, fy);
                fz = fmaf(dz, w, fz);
            }
            float dvx = fmaf(coupling, fx, fmaf(-damping, vx, sDn[t*8+3]));
            float dvy = fmaf(coupling, fy, fmaf(-damping, vy, sDn[t*8+4]));
            float dvz = fmaf(coupling, fz, fmaf(-damping, vz, sDn[t*8+5]));
            float dsz = fmaf(-0.05f, (sz  - 1.0f), sDn[t*8+6]);
            float din = fmaf(-0.05f, (in_ - 0.5f), sDn[t*8+7]);
            nxt[t*8+0] = fmaf(adt, vx,  px);
            nxt[t*8+1] = fmaf(adt, vy,  py);
            nxt[t*8+2] = fmaf(adt, vz,  pz);
            nxt[t*8+3] = fmaf(adt, dvx, vx);
            nxt[t*8+4] = fmaf(adt, dvy, vy);
            nxt[t*8+5] = fmaf(adt, dvz, vz);
            nxt[t*8+6] = fmaf(adt, dsz, sz);
            nxt[t*8+7] = fmaf(adt, din, in_);
        }
        __syncthreads();
        float* tmp = cur; cur = nxt; nxt = tmp;
    }

    // summary = summ_w @ flat + summ_b
    if (t < 32){
        float a = summ_b[t];
        for (int k = 0; k < SDIM; ++k) a = fmaf(summ_w[t*SDIM + k], cur[k], a);
        sSum[t] = a;
    }
    __syncthreads();

    // pack field weights + fold summary into effective biases
    for (int idx = t; idx < 64*24; idx += 256){
        int jj = idx / 24, k = idx % 24;
        ws[WS_FQW  + idx] = fq_w1[jj*56 + k];
        ws[WS_COLW + idx] = col_w1[jj*57 + k];
    }
    if (t < 64){
        float bq = fq_b1[t], bc = col_b1[t];
        #pragma unroll
        for (int m = 0; m < 32; ++m){
            bq = fmaf(sSum[m], fq_w1[t*56 + 24 + m], bq);
            bc = fmaf(sSum[m], col_w1[t*57 + 24 + m], bc);
        }
        ws[WS_FQB   + t] = bq;
        ws[WS_COLB  + t] = bc;
        ws[WS_COLWD + t] = col_w1[t*57 + 56];
        ws[WS_FQW2  + t] = fq_w2[t];
        ws[WS_COLW2 + t]       = col_w2[t];
        ws[WS_COLW2 + 64 + t]  = col_w2[64 + t];
        ws[WS_COLW2 + 128 + t] = col_w2[128 + t];
    }
    if (t == 0){
        ws[WS_MISC + 0] = fq_b2[0];
        ws[WS_MISC + 1] = col_b2[0];
        ws[WS_MISC + 2] = col_b2[1];
        ws[WS_MISC + 3] = col_b2[2];
    }
}

__global__ __launch_bounds__(256) void field_kernel(
    const float* __restrict__ p,
    const float* __restrict__ ws,
    float* __restrict__ out, int N)
{
    const int i = blockIdx.x * 256 + threadIdx.x;
    if (i >= N) return;

    const float x0 = p[3*i], x1 = p[3*i+1], x2 = p[3*i+2];
    float penc[24];
    #pragma unroll
    for (int f = 0; f < 4; ++f){
        const float fr = (float)(1 << f);
        float s, c;
        __sincosf(TWO_PI_F * fr * x0, &s, &c); penc[f*6+0] = s; penc[f*6+3] = c;
        __sincosf(TWO_PI_F * fr * x1, &s, &c); penc[f*6+1] = s; penc[f*6+4] = c;
        __sincosf(TWO_PI_F * fr * x2, &s, &c); penc[f*6+2] = s; penc[f*6+5] = c;
    }

    const float* Wq  = ws + WS_FQW;
    const float* Wc  = ws + WS_COLW;
    const float* Bq  = ws + WS_FQB;
    const float* Bc  = ws + WS_COLB;
    const float* Wd  = ws + WS_COLWD;
    const float* W2q = ws + WS_FQW2;
    const float* W2c = ws + WS_COLW2;

    // density MLP (summary folded into Bq)
    float dacc = ws[WS_MISC + 0];
    #pragma unroll 4
    for (int jj = 0; jj < 64; ++jj){
        float a = Bq[jj];
        #pragma unroll
        for (int k = 0; k < 24; ++k) a = fmaf(penc[k], Wq[jj*24 + k], a);
        a = fmaxf(a, 0.0f);
        dacc = fmaf(a, W2q[jj], dacc);
    }
    const float density = fast_softplus(dacc);

    // color MLP (summary folded into Bc; density via Wd)
    float c0 = ws[WS_MISC + 1], c1 = ws[WS_MISC + 2], c2 = ws[WS_MISC + 3];
    #pragma unroll 4
    for (int jj = 0; jj < 64; ++jj){
        float a = Bc[jj];
        #pragma unroll
        for (int k = 0; k < 24; ++k) a = fmaf(penc[k], Wc[jj*24 + k], a);
        a = fmaf(density, Wd[jj], a);
        a = fmaxf(a, 0.0f);
        c0 = fmaf(a, W2c[jj],       c0);
        c1 = fmaf(a, W2c[64 + jj],  c1);
        c2 = fmaf(a, W2c[128 + jj], c2);
    }

    out[i] = density;
    float* oc = out + N;
    oc[3*i + 0] = fast_sigmoid(c0);
    oc[3*i + 1] = fast_sigmoid(c1);
    oc[3*i + 2] = fast_sigmoid(c2);
}

extern "C" void kernel_launch(void* const* d_in, const int* in_sizes, int n_in,
                              void* d_out, int out_size, void* d_ws, size_t ws_size,
                              hipStream_t stream)
{
    const float* p             = (const float*)d_in[0];
    const float* initial_state = (const float*)d_in[1];
    const float* dyn_w1        = (const float*)d_in[2];
    const float* dyn_b1        = (const float*)d_in[3];
    const float* dyn_w2        = (const float*)d_in[4];
    const float* dyn_b2        = (const float*)d_in[5];
    const float* coupling      = (const float*)d_in[6];
    const float* damping       = (const float*)d_in[7];
    const float* interaction   = (const float*)d_in[8];
    const float* summ_w        = (const float*)d_in[9];
    const float* summ_b        = (const float*)d_in[10];
    const float* fq_w1         = (const float*)d_in[11];
    const float* fq_b1         = (const float*)d_in[12];
    const float* fq_w2         = (const float*)d_in[13];
    const float* fq_b2         = (const float*)d_in[14];
    const float* col_w1        = (const float*)d_in[15];
    const float* col_b1        = (const float*)d_in[16];
    const float* col_w2        = (const float*)d_in[17];
    const float* col_b2        = (const float*)d_in[18];
    const int*   tP            = (const int*)d_in[19];

    float* ws  = (float*)d_ws;
    float* out = (float*)d_out;
    const int N = in_sizes[0] / 3;

    hipLaunchKernelGGL(blob_sim_kernel, dim3(1), dim3(256), 0, stream,
                       initial_state, dyn_w1, dyn_b1, dyn_w2, dyn_b2,
                       coupling, damping, interaction, summ_w, summ_b,
                       fq_w1, fq_b1, fq_w2, fq_b2,
                       col_w1, col_b1, col_w2, col_b2, tP, ws);

    const int blocks = (N + 255) / 256;
    hipLaunchKernelGGL(field_kernel, dim3(blocks), dim3(256), 0, stream,
                       p, ws, out, N);
}

// Round 2
// 860.720 us; speedup vs baseline: 1.0759x; 1.0759x over previous
//
#include <hip/hip_runtime.h>
#include <math.h>

#define NB 20
#define SDIM 160   // 20*8
#define H1 64
#define TWO_PI_F 6.28318530717958647692f

// ws layout (floats)
#define WS_FQW   0      // [64][24]
#define WS_COLW  1536   // [64][24]
#define WS_FQB   3072   // [64] effective bias (b + summary part)
#define WS_COLB  3136   // [64]
#define WS_COLWD 3200   // [64] col_w1[j][56] (density weight)
#define WS_FQW2  3264   // [64]
#define WS_COLW2 3328   // [3][64]
#define WS_MISC  3520   // [0]=fq_b2, [1..3]=col_b2

__device__ __forceinline__ float fast_sigmoid(float x){ return 1.0f/(1.0f+__expf(-x)); }
__device__ __forceinline__ float fast_softplus(float x){
    return fmaxf(x, 0.0f) + __logf(1.0f + __expf(-fabsf(x)));
}
__device__ __forceinline__ float fast_rcp(float x){ return __builtin_amdgcn_rcpf(x); }
__device__ __forceinline__ float fast_rsq(float x){ return __builtin_amdgcn_rsqf(x); }
__device__ __forceinline__ float bperm(float v, int srcLane){
    return __int_as_float(__builtin_amdgcn_ds_bpermute(srcLane << 2, __float_as_int(v)));
}

// ---------------------------------------------------------------------------
// Single-wave blob simulation: 64 lanes, zero barriers. All LDS ops from one
// wave execute in program order, so no __syncthreads is ever needed.
// ---------------------------------------------------------------------------
__global__ __launch_bounds__(64) void blob_sim_kernel(
    const float* __restrict__ initial_state,
    const float* __restrict__ dyn_w1, const float* __restrict__ dyn_b1,
    const float* __restrict__ dyn_w2, const float* __restrict__ dyn_b2,
    const float* __restrict__ couplingP, const float* __restrict__ dampingP,
    const float* __restrict__ interaction,
    const float* __restrict__ summ_w, const float* __restrict__ summ_b,
    const float* __restrict__ fq_w1, const float* __restrict__ fq_b1,
    const float* __restrict__ fq_w2, const float* __restrict__ fq_b2,
    const float* __restrict__ col_w1, const float* __restrict__ col_b1,
    const float* __restrict__ col_w2, const float* __restrict__ col_b2,
    const int* __restrict__ tP,
    float* __restrict__ ws)
{
    // W1 packed [k4][j][q] : k = k4*4+q.  lane j reads one b128 per k4.
    __shared__ float sW1p[40*256];          // 40 KB
    // W2 packed [k4][o][q], only the 100 used dneural outputs, padded to 128.
    __shared__ float sW2p[16*512];          // 32 KB
    __shared__ float sB1[H1];
    __shared__ float sB2p[100];
    __shared__ float sInter[NB*NB];
    __shared__ float sS[SDIM];
    __shared__ float sH[H1];
    __shared__ float sDn[100];
    __shared__ float sF[NB*3];
    __shared__ float sSum[32];

    const int lane = threadIdx.x;

    // ---- one-time packing ----
    for (int idx = lane; idx < 40*256; idx += 64){
        int k4 = idx >> 8, rem = idx & 255;
        int j = rem >> 2, q = rem & 3;
        sW1p[idx] = dyn_w1[j*SDIM + k4*4 + q];
    }
    for (int idx = lane; idx < 16*512; idx += 64){
        int k4 = idx >> 9, rem = idx & 511;
        int o = rem >> 2, q = rem & 3;
        float v = 0.0f;
        if (o < 100){
            int b = o / 5, cc = 3 + (o % 5);
            v = dyn_w2[(b*8 + cc)*H1 + k4*4 + q];
        }
        sW2p[idx] = v;
    }
    sB1[lane] = dyn_b1[lane];
    for (int o = lane; o < 100; o += 64){
        int b = o / 5, cc = 3 + (o % 5);
        sB2p[o] = dyn_b2[b*8 + cc];
    }
    for (int idx = lane; idx < NB*NB; idx += 64) sInter[idx] = interaction[idx];
    for (int idx = lane; idx < SDIM;  idx += 64) sS[idx] = initial_state[idx];

    const float coupling = couplingP[0];
    const float damping  = dampingP[0];
    const int tv = tP[0];
    int n_steps = (int)((double)tv / 0.01);   // replicates Python int(t/DT): 2 -> 199
    if (n_steps < 1) n_steps = 1;
    const float adt = (float)((double)tv / (double)n_steps);

    // force-lane decomposition: g = lane/20 covers jj ranges 0..6 / 7..13 / 14..19
    const int g  = lane / 20;
    const int fi = lane - g*20;
    const int jj0 = g * 7;

    for (int step = 0; step < n_steps; ++step){
        // ---- phase 1: h = tanh(W1 @ s + b1), lane j owns h_j ----
        float a0 = 0.f, a1 = 0.f, a2 = 0.f, a3 = 0.f;
        #pragma unroll
        for (int k4 = 0; k4 < 40; ++k4){
            float4 s4 = *(const float4*)&sS[k4*4];                 // broadcast
            float4 w4 = *(const float4*)&sW1p[k4*256 + lane*4];    // stride-1 b128
            a0 = fmaf(s4.x, w4.x, a0);
            a1 = fmaf(s4.y, w4.y, a1);
            a2 = fmaf(s4.z, w4.z, a2);
            a3 = fmaf(s4.w, w4.w, a3);
        }
        float hv = (a0 + a1) + (a2 + a3) + sB1[lane];
        hv = fminf(fmaxf(hv, -15.0f), 15.0f);
        float e2 = __expf(2.0f * hv);
        float hj = (e2 - 1.0f) * fast_rcp(e2 + 1.0f);
        sH[lane] = hj;

        // ---- forces (independent of h; hides sH turnaround latency) ----
        float fx = 0.f, fy = 0.f, fz = 0.f;
        {
            const float px = sS[fi*8+0], py = sS[fi*8+1], pz = sS[fi*8+2];
            #pragma unroll
            for (int jc = 0; jc < 7; ++jc){
                int jj = jj0 + jc;
                if (jj < NB){
                    float dx = px - sS[jj*8+0];
                    float dy = py - sS[jj*8+1];
                    float dz = pz - sS[jj*8+2];
                    float e  = fmaf(dx,dx, fmaf(dy,dy, fmaf(dz,dz, 1e-6f)));
                    float d  = e * fast_rsq(e);
                    float mag = sInter[fi*NB + jj] * fast_rcp(e + 1.0f);
                    float w   = mag * fast_rcp(d + 1e-6f);
                    fx = fmaf(dx, w, fx);
                    fy = fmaf(dy, w, fy);
                    fz = fmaf(dz, w, fz);
                }
            }
        }
        // reduce the 3 partial groups into lanes 0..19
        fx += bperm(fx, lane+20) + bperm(fx, lane+40);
        fy += bperm(fy, lane+20) + bperm(fy, lane+40);
        fz += bperm(fz, lane+20) + bperm(fz, lane+40);
        if (lane < NB){
            sF[fi*3+0] = fx;
            sF[fi*3+1] = fy;
            sF[fi*3+2] = fz;
        }

        // ---- phase 2: dn (100 used outputs) = W2p @ h + b2p ----
        float b0=0.f,b1=0.f,b2=0.f,b3=0.f;   // output o1 = lane
        float c0=0.f,c1=0.f,c2=0.f,c3=0.f;   // output o2 = 64+lane (lane<36)
        #pragma unroll
        for (int k4 = 0; k4 < 16; ++k4){
            float4 h4 = *(const float4*)&sH[k4*4];                 // broadcast
            float4 wA = *(const float4*)&sW2p[k4*512 + lane*4];
            float4 wB = *(const float4*)&sW2p[k4*512 + (64+lane)*4];
            b0 = fmaf(h4.x, wA.x, b0); b1 = fmaf(h4.y, wA.y, b1);
            b2 = fmaf(h4.z, wA.z, b2); b3 = fmaf(h4.w, wA.w, b3);
            c0 = fmaf(h4.x, wB.x, c0); c1 = fmaf(h4.y, wB.y, c1);
            c2 = fmaf(h4.z, wB.z, c2); c3 = fmaf(h4.w, wB.w, c3);
        }
        sDn[lane] = (b0+b1) + (b2+b3) + sB2p[lane];
        if (lane < 36) sDn[64+lane] = (c0+c1) + (c2+c3) + sB2p[64+lane];

        // ---- update: 160 elements over 3 passes, single state buffer ----
        #pragma unroll
        for (int pass = 0; pass < 3; ++pass){
            int i = pass*64 + lane;
            if (i < SDIM){
                int cc = i & 7, b = i >> 3;
                float cv = sS[i];
                float dv;
                if (cc < 3)      dv = sS[i+3];
                else if (cc < 6) dv = fmaf(-damping, cv,
                                     fmaf(coupling, sF[b*3 + cc-3], sDn[b*5 + cc-3]));
                else if (cc == 6) dv = fmaf(-0.05f, cv - 1.0f, sDn[b*5+3]);
                else              dv = fmaf(-0.05f, cv - 0.5f, sDn[b*5+4]);
                sS[i] = fmaf(adt, dv, cv);
            }
        }
    }

    // ---- summary = summ_w @ flat + summ_b ----
    if (lane < 32){
        float a = summ_b[lane];
        for (int k = 0; k < SDIM; ++k) a = fmaf(summ_w[lane*SDIM + k], sS[k], a);
        sSum[lane] = a;
    }

    // ---- pack field weights + fold summary into effective biases ----
    for (int idx = lane; idx < 64*24; idx += 64){
        int jj = idx / 24, k = idx % 24;
        ws[WS_FQW  + idx] = fq_w1[jj*56 + k];
        ws[WS_COLW + idx] = col_w1[jj*57 + k];
    }
    {
        float bq = fq_b1[lane], bc = col_b1[lane];
        #pragma unroll
        for (int m = 0; m < 32; ++m){
            bq = fmaf(sSum[m], fq_w1[lane*56 + 24 + m], bq);
            bc = fmaf(sSum[m], col_w1[lane*57 + 24 + m], bc);
        }
        ws[WS_FQB   + lane] = bq;
        ws[WS_COLB  + lane] = bc;
        ws[WS_COLWD + lane] = col_w1[lane*57 + 56];
        ws[WS_FQW2  + lane] = fq_w2[lane];
        ws[WS_COLW2 + lane]       = col_w2[lane];
        ws[WS_COLW2 + 64 + lane]  = col_w2[64 + lane];
        ws[WS_COLW2 + 128 + lane] = col_w2[128 + lane];
    }
    if (lane == 0){
        ws[WS_MISC + 0] = fq_b2[0];
        ws[WS_MISC + 1] = col_b2[0];
        ws[WS_MISC + 2] = col_b2[1];
        ws[WS_MISC + 3] = col_b2[2];
    }
}

__global__ __launch_bounds__(256) void field_kernel(
    const float* __restrict__ p,
    const float* __restrict__ ws,
    float* __restrict__ out, int N)
{
    const int i = blockIdx.x * 256 + threadIdx.x;
    if (i >= N) return;

    const float x0 = p[3*i], x1 = p[3*i+1], x2 = p[3*i+2];
    float penc[24];
    #pragma unroll
    for (int f = 0; f < 4; ++f){
        const float fr = (float)(1 << f);
        float s, c;
        __sincosf(TWO_PI_F * fr * x0, &s, &c); penc[f*6+0] = s; penc[f*6+3] = c;
        __sincosf(TWO_PI_F * fr * x1, &s, &c); penc[f*6+1] = s; penc[f*6+4] = c;
        __sincosf(TWO_PI_F * fr * x2, &s, &c); penc[f*6+2] = s; penc[f*6+5] = c;
    }

    const float* Wq  = ws + WS_FQW;
    const float* Wc  = ws + WS_COLW;
    const float* Bq  = ws + WS_FQB;
    const float* Bc  = ws + WS_COLB;
    const float* Wd  = ws + WS_COLWD;
    const float* W2q = ws + WS_FQW2;
    const float* W2c = ws + WS_COLW2;

    // density MLP (summary folded into Bq)
    float dacc = ws[WS_MISC + 0];
    #pragma unroll 4
    for (int jj = 0; jj < 64; ++jj){
        float a = Bq[jj];
        #pragma unroll
        for (int k = 0; k < 24; ++k) a = fmaf(penc[k], Wq[jj*24 + k], a);
        a = fmaxf(a, 0.0f);
        dacc = fmaf(a, W2q[jj], dacc);
    }
    const float density = fast_softplus(dacc);

    // color MLP (summary folded into Bc; density via Wd)
    float c0 = ws[WS_MISC + 1], c1 = ws[WS_MISC + 2], c2 = ws[WS_MISC + 3];
    #pragma unroll 4
    for (int jj = 0; jj < 64; ++jj){
        float a = Bc[jj];
        #pragma unroll
        for (int k = 0; k < 24; ++k) a = fmaf(penc[k], Wc[jj*24 + k], a);
        a = fmaf(density, Wd[jj], a);
        a = fmaxf(a, 0.0f);
        c0 = fmaf(a, W2c[jj],       c0);
        c1 = fmaf(a, W2c[64 + jj],  c1);
        c2 = fmaf(a, W2c[128 + jj], c2);
    }

    out[i] = density;
    float* oc = out + N;
    oc[3*i + 0] = fast_sigmoid(c0);
    oc[3*i + 1] = fast_sigmoid(c1);
    oc[3*i + 2] = fast_sigmoid(c2);
}

extern "C" void kernel_launch(void* const* d_in, const int* in_sizes, int n_in,
                              void* d_out, int out_size, void* d_ws, size_t ws_size,
                              hipStream_t stream)
{
    const float* p             = (const float*)d_in[0];
    const float* initial_state = (const float*)d_in[1];
    const float* dyn_w1        = (const float*)d_in[2];
    const float* dyn_b1        = (const float*)d_in[3];
    const float* dyn_w2        = (const float*)d_in[4];
    const float* dyn_b2        = (const float*)d_in[5];
    const float* coupling      = (const float*)d_in[6];
    const float* damping       = (const float*)d_in[7];
    const float* interaction   = (const float*)d_in[8];
    const float* summ_w        = (const float*)d_in[9];
    const float* summ_b        = (const float*)d_in[10];
    const float* fq_w1         = (const float*)d_in[11];
    const float* fq_b1         = (const float*)d_in[12];
    const float* fq_w2         = (const float*)d_in[13];
    const float* fq_b2         = (const float*)d_in[14];
    const float* col_w1        = (const float*)d_in[15];
    const float* col_b1        = (const float*)d_in[16];
    const float* col_w2        = (const float*)d_in[17];
    const float* col_b2        = (const float*)d_in[18];
    const int*   tP            = (const int*)d_in[19];

    float* ws  = (float*)d_ws;
    float* out = (float*)d_out;
    const int N = in_sizes[0] / 3;

    hipLaunchKernelGGL(blob_sim_kernel, dim3(1), dim3(64), 0, stream,
                       initial_state, dyn_w1, dyn_b1, dyn_w2, dyn_b2,
                       coupling, damping, interaction, summ_w, summ_b,
                       fq_w1, fq_b1, fq_w2, fq_b2,
                       col_w1, col_b1, col_w2, col_b2, tP, ws);

    const int blocks = (N + 255) / 256;
    hipLaunchKernelGGL(field_kernel, dim3(blocks), dim3(256), 0, stream,
                       p, ws, out, N);
}

// Round 3
// 847.382 us; speedup vs baseline: 1.0929x; 1.0157x over previous
//
#include <hip/hip_runtime.h>
#include <math.h>

#define NB 20
#define SDIM 160   // 20*8
#define H1 64
#define TWO_PI_F 6.28318530717958647692f

// ws layout (floats)
#define WS_FQW   0      // [64][24]
#define WS_COLW  1536   // [64][24]
#define WS_FQB   3072   // [64] effective bias (b + summary part)
#define WS_COLB  3136   // [64]
#define WS_COLWD 3200   // [64] col_w1[j][56] (density weight)
#define WS_FQW2  3264   // [64]
#define WS_COLW2 3328   // [3][64]
#define WS_MISC  3520   // [0]=fq_b2, [1..3]=col_b2

__device__ __forceinline__ float fast_sigmoid(float x){ return 1.0f/(1.0f+__expf(-x)); }
__device__ __forceinline__ float fast_softplus(float x){
    return fmaxf(x, 0.0f) + __logf(1.0f + __expf(-fabsf(x)));
}
__device__ __forceinline__ float fast_rcp(float x){ return __builtin_amdgcn_rcpf(x); }
__device__ __forceinline__ float fast_rsq(float x){ return __builtin_amdgcn_rsqf(x); }
__device__ __forceinline__ float bperm(float v, int srcLane){
    return __int_as_float(__builtin_amdgcn_ds_bpermute(srcLane << 2, __float_as_int(v)));
}
__device__ __forceinline__ float rdlane(float v, int l){
    return __int_as_float(__builtin_amdgcn_readlane(__float_as_int(v), l));
}
// state element f (0..159) broadcast from its owning lane's register
__device__ __forceinline__ float getS(float s0, float s1, float s2, int f){
    return (f < 64) ? rdlane(s0, f) : (f < 128) ? rdlane(s1, f - 64) : rdlane(s2, f - 128);
}

// ---------------------------------------------------------------------------
// Single-wave, register-resident blob simulation.
// Weights live in VGPRs (lane j owns W1 row j and W2-used rows j, 64+j).
// Per-step matvecs = v_readlane broadcasts + v_fmac. ~10 LDS ops/step total.
// ---------------------------------------------------------------------------
__global__ __launch_bounds__(64, 1) void blob_sim_kernel(
    const float* __restrict__ initial_state,
    const float* __restrict__ dyn_w1, const float* __restrict__ dyn_b1,
    const float* __restrict__ dyn_w2, const float* __restrict__ dyn_b2,
    const float* __restrict__ couplingP, const float* __restrict__ dampingP,
    const float* __restrict__ interaction,
    const float* __restrict__ summ_w, const float* __restrict__ summ_b,
    const float* __restrict__ fq_w1, const float* __restrict__ fq_b1,
    const float* __restrict__ fq_w2, const float* __restrict__ fq_b2,
    const float* __restrict__ col_w1, const float* __restrict__ col_b1,
    const float* __restrict__ col_w2, const float* __restrict__ col_b2,
    const int* __restrict__ tP,
    float* __restrict__ ws)
{
    __shared__ float sW1T[160*64];   // [k][j] transpose staging (40 KB)
    __shared__ float sW2T[64*128];   // [k][o padded to 128] (32 KB)
    __shared__ float sPos[64];       // current positions [b*3+c], b<20
    __shared__ float sFr[64];        // forces [b*3+c]
    __shared__ float sSum[32];

    const int lane = threadIdx.x;

    // ---- one-time: stage transposes coalesced, pull into registers ----
    for (int idx = lane; idx < 160*64; idx += 64){
        int j = idx / 160, k = idx - j*160;
        sW1T[k*64 + j] = dyn_w1[idx];
    }
    for (int idx = lane; idx < 64*100; idx += 64){
        int k = idx / 100, o = idx - k*100;
        int ob = o / 5, oc = o - ob*5;
        sW2T[k*128 + o] = dyn_w2[(ob*8 + 3 + oc)*H1 + k];
    }

    float w1[160];
    #pragma unroll
    for (int k = 0; k < 160; ++k) w1[k] = sW1T[k*64 + lane];

    float w2a[64], w2b[64];
    #pragma unroll
    for (int k = 0; k < 64; ++k){
        w2a[k] = sW2T[k*128 + lane];
        w2b[k] = sW2T[k*128 + 64 + lane];   // lanes>=36 read pad: unused garbage
    }

    float rint[20];
    {
        int rb = (lane < NB ? lane : 0) * NB;
        #pragma unroll
        for (int jj = 0; jj < NB; ++jj) rint[jj] = interaction[rb + jj];
    }

    if (lane < 60) sPos[lane] = initial_state[(lane/3)*8 + (lane - (lane/3)*3)];

    float s0 = initial_state[lane];
    float s1 = initial_state[64 + lane];
    float s2 = (lane < 32) ? initial_state[128 + lane] : 0.0f;

    const float b1r = dyn_b1[lane];
    float b2ar, b2br;
    { int b = lane/5, c = lane - b*5; b2ar = dyn_b2[b*8 + 3 + c]; }
    { int o2 = 64 + lane;
      if (o2 < 100){ int b = o2/5, c = o2 - b*5; b2br = dyn_b2[b*8 + 3 + c]; }
      else b2br = 0.0f; }

    const float coupling = couplingP[0];
    const float damping  = dampingP[0];
    const int tv = tP[0];
    int n_steps = (int)((double)tv / 0.01);   // replicates Python int(t/DT): 2 -> 199
    if (n_steps < 1) n_steps = 1;
    const float adt = (float)((double)tv / (double)n_steps);

    const int cc  = lane & 7;
    const int bb  = lane >> 3;
    const int cm3 = (cc >= 3) ? cc - 3 : 0;
    const int lp3 = (lane + 3 > 63) ? 63 : lane + 3;
    const int fb  = (lane < NB ? lane : 0) * 3;

    for (int step = 0; step < n_steps; ++step){
        // ---- phase 1: h = tanh(W1 @ s + b1); all-register ----
        float a0=0.f, a1=0.f, a2=0.f, a3=0.f;
        #pragma unroll
        for (int k = 0; k < 64; k += 4){
            a0 = fmaf(rdlane(s0,k),   w1[k],   a0);
            a1 = fmaf(rdlane(s0,k+1), w1[k+1], a1);
            a2 = fmaf(rdlane(s0,k+2), w1[k+2], a2);
            a3 = fmaf(rdlane(s0,k+3), w1[k+3], a3);
        }
        #pragma unroll
        for (int k = 0; k < 64; k += 4){
            a0 = fmaf(rdlane(s1,k),   w1[64+k],   a0);
            a1 = fmaf(rdlane(s1,k+1), w1[64+k+1], a1);
            a2 = fmaf(rdlane(s1,k+2), w1[64+k+2], a2);
            a3 = fmaf(rdlane(s1,k+3), w1[64+k+3], a3);
        }
        #pragma unroll
        for (int k = 0; k < 32; k += 4){
            a0 = fmaf(rdlane(s2,k),   w1[128+k],   a0);
            a1 = fmaf(rdlane(s2,k+1), w1[128+k+1], a1);
            a2 = fmaf(rdlane(s2,k+2), w1[128+k+2], a2);
            a3 = fmaf(rdlane(s2,k+3), w1[128+k+3], a3);
        }
        float hv = (a0+a1) + (a2+a3) + b1r;
        hv = fminf(fmaxf(hv, -15.0f), 15.0f);
        float e2v = __expf(2.0f * hv);
        float hreg = (e2v - 1.0f) * fast_rcp(e2v + 1.0f);

        // ---- forces: lane fi<20 computes its full row; positions via readlane ----
        float px = sPos[fb], py = sPos[fb+1], pz = sPos[fb+2];
        float fx=0.f, fy=0.f, fz=0.f;
        #pragma unroll
        for (int jj = 0; jj < NB; ++jj){
            float xj = getS(s0,s1,s2, jj*8+0);
            float yj = getS(s0,s1,s2, jj*8+1);
            float zj = getS(s0,s1,s2, jj*8+2);
            float dx = px-xj, dy = py-yj, dz = pz-zj;
            float e  = fmaf(dx,dx, fmaf(dy,dy, fmaf(dz,dz, 1e-6f)));
            float d  = e * fast_rsq(e);
            float mag = rint[jj] * fast_rcp(e + 1.0f);
            float w   = mag * fast_rcp(d + 1e-6f);
            fx = fmaf(dx, w, fx);
            fy = fmaf(dy, w, fy);
            fz = fmaf(dz, w, fz);
        }
        if (lane < NB){
            sFr[lane*3+0] = fx; sFr[lane*3+1] = fy; sFr[lane*3+2] = fz;
        }

        // ---- phase 2: dn = W2used @ h + b2 (outputs lane, 64+lane) ----
        float d0=0.f, d1=0.f, g0=0.f, g1=0.f;
        #pragma unroll
        for (int k = 0; k < 64; k += 2){
            float h0 = rdlane(hreg, k), h1 = rdlane(hreg, k+1);
            d0 = fmaf(h0, w2a[k],   d0);
            d1 = fmaf(h1, w2a[k+1], d1);
            g0 = fmaf(h0, w2b[k],   g0);
            g1 = fmaf(h1, w2b[k+1], g1);
        }
        float dnA = d0 + d1 + b2ar;             // dn[o=lane]
        float dnB = g0 + g1 + b2br;             // dn[o=64+lane], valid lane<36

        // ---- update (gathers read OLD state/dn) ----
        float v0 = bperm(s0, lp3);
        float v1 = bperm(s1, lp3);
        float v2 = bperm(s2, lp3);
        int o0 = bb*5 + cm3;                    // < 40
        int o1 = 40 + bb*5 + cm3;               // 40..79
        int o2 = 80 + bb*5 + cm3;               // 80..99 (lane<32)
        float dn0  = bperm(dnA, o0);
        float dn1a = bperm(dnA, (o1 < 64) ? o1 : 0);
        float dn1b = bperm(dnB, (o1 >= 64) ? o1 - 64 : 0);
        float dn1  = (o1 < 64) ? dn1a : dn1b;
        float dn2  = bperm(dnB, o2 - 64);       // lanes 16..35
        float F0 = sFr[bb*3 + cm3];
        float F1 = sFr[(8+bb)*3 + cm3];
        float F2 = sFr[(lane < 32) ? (16+bb)*3 + cm3 : 0];

        float dv0 = (cc < 3) ? v0
                  : (cc < 6) ? fmaf(-damping, s0, fmaf(coupling, F0, dn0))
                  : (cc == 6) ? fmaf(-0.05f, s0 - 1.0f, dn0)
                              : fmaf(-0.05f, s0 - 0.5f, dn0);
        float dv1 = (cc < 3) ? v1
                  : (cc < 6) ? fmaf(-damping, s1, fmaf(coupling, F1, dn1))
                  : (cc == 6) ? fmaf(-0.05f, s1 - 1.0f, dn1)
                              : fmaf(-0.05f, s1 - 0.5f, dn1);
        float dv2 = (cc < 3) ? v2
                  : (cc < 6) ? fmaf(-damping, s2, fmaf(coupling, F2, dn2))
                  : (cc == 6) ? fmaf(-0.05f, s2 - 1.0f, dn2)
                              : fmaf(-0.05f, s2 - 0.5f, dn2);

        s0 = fmaf(adt, dv0, s0);
        s1 = fmaf(adt, dv1, s1);
        s2 = fmaf(adt, dv2, s2);

        if (cc < 3){
            sPos[bb*3 + cc]      = s0;
            sPos[(8+bb)*3 + cc]  = s1;
            if (lane < 32) sPos[(16+bb)*3 + cc] = s2;
        }
    }

    // ---- summary = summ_w @ flat + summ_b (rows on lanes 0..31) ----
    {
        int sbase = (lane & 31) * SDIM;
        float sa = summ_b[lane & 31];
        #pragma unroll
        for (int k = 0; k < SDIM; ++k)
            sa = fmaf(getS(s0,s1,s2,k), summ_w[sbase + k], sa);
        if (lane < 32) sSum[lane] = sa;
    }

    // ---- pack field weights + fold summary into effective biases ----
    for (int idx = lane; idx < 64*24; idx += 64){
        int jj = idx / 24, k = idx - jj*24;
        ws[WS_FQW  + idx] = fq_w1[jj*56 + k];
        ws[WS_COLW + idx] = col_w1[jj*57 + k];
    }
    {
        float bq = fq_b1[lane], bc = col_b1[lane];
        #pragma unroll
        for (int m = 0; m < 32; ++m){
            bq = fmaf(sSum[m], fq_w1[lane*56 + 24 + m], bq);
            bc = fmaf(sSum[m], col_w1[lane*57 + 24 + m], bc);
        }
        ws[WS_FQB   + lane] = bq;
        ws[WS_COLB  + lane] = bc;
        ws[WS_COLWD + lane] = col_w1[lane*57 + 56];
        ws[WS_FQW2  + lane] = fq_w2[lane];
        ws[WS_COLW2 + lane]       = col_w2[lane];
        ws[WS_COLW2 + 64 + lane]  = col_w2[64 + lane];
        ws[WS_COLW2 + 128 + lane] = col_w2[128 + lane];
    }
    if (lane == 0){
        ws[WS_MISC + 0] = fq_b2[0];
        ws[WS_MISC + 1] = col_b2[0];
        ws[WS_MISC + 2] = col_b2[1];
        ws[WS_MISC + 3] = col_b2[2];
    }
}

__global__ __launch_bounds__(256) void field_kernel(
    const float* __restrict__ p,
    const float* __restrict__ ws,
    float* __restrict__ out, int N)
{
    const int i = blockIdx.x * 256 + threadIdx.x;
    if (i >= N) return;

    const float x0 = p[3*i], x1 = p[3*i+1], x2 = p[3*i+2];
    float penc[24];
    #pragma unroll
    for (int f = 0; f < 4; ++f){
        const float fr = (float)(1 << f);
        float s, c;
        __sincosf(TWO_PI_F * fr * x0, &s, &c); penc[f*6+0] = s; penc[f*6+3] = c;
        __sincosf(TWO_PI_F * fr * x1, &s, &c); penc[f*6+1] = s; penc[f*6+4] = c;
        __sincosf(TWO_PI_F * fr * x2, &s, &c); penc[f*6+2] = s; penc[f*6+5] = c;
    }

    const float* Wq  = ws + WS_FQW;
    const float* Wc  = ws + WS_COLW;
    const float* Bq  = ws + WS_FQB;
    const float* Bc  = ws + WS_COLB;
    const float* Wd  = ws + WS_COLWD;
    const float* W2q = ws + WS_FQW2;
    const float* W2c = ws + WS_COLW2;

    // density MLP (summary folded into Bq)
    float dacc = ws[WS_MISC + 0];
    #pragma unroll 4
    for (int jj = 0; jj < 64; ++jj){
        float a = Bq[jj];
        #pragma unroll
        for (int k = 0; k < 24; ++k) a = fmaf(penc[k], Wq[jj*24 + k], a);
        a = fmaxf(a, 0.0f);
        dacc = fmaf(a, W2q[jj], dacc);
    }
    const float density = fast_softplus(dacc);

    // color MLP (summary folded into Bc; density via Wd)
    float c0 = ws[WS_MISC + 1], c1 = ws[WS_MISC + 2], c2 = ws[WS_MISC + 3];
    #pragma unroll 4
    for (int jj = 0; jj < 64; ++jj){
        float a = Bc[jj];
        #pragma unroll
        for (int k = 0; k < 24; ++k) a = fmaf(penc[k], Wc[jj*24 + k], a);
        a = fmaf(density, Wd[jj], a);
        a = fmaxf(a, 0.0f);
        c0 = fmaf(a, W2c[jj],       c0);
        c1 = fmaf(a, W2c[64 + jj],  c1);
        c2 = fmaf(a, W2c[128 + jj], c2);
    }

    out[i] = density;
    float* oc = out + N;
    oc[3*i + 0] = fast_sigmoid(c0);
    oc[3*i + 1] = fast_sigmoid(c1);
    oc[3*i + 2] = fast_sigmoid(c2);
}

extern "C" void kernel_launch(void* const* d_in, const int* in_sizes, int n_in,
                              void* d_out, int out_size, void* d_ws, size_t ws_size,
                              hipStream_t stream)
{
    const float* p             = (const float*)d_in[0];
    const float* initial_state = (const float*)d_in[1];
    const float* dyn_w1        = (const float*)d_in[2];
    const float* dyn_b1        = (const float*)d_in[3];
    const float* dyn_w2        = (const float*)d_in[4];
    const float* dyn_b2        = (const float*)d_in[5];
    const float* coupling      = (const float*)d_in[6];
    const float* damping       = (const float*)d_in[7];
    const float* interaction   = (const float*)d_in[8];
    const float* summ_w        = (const float*)d_in[9];
    const float* summ_b        = (const float*)d_in[10];
    const float* fq_w1         = (const float*)d_in[11];
    const float* fq_b1         = (const float*)d_in[12];
    const float* fq_w2         = (const float*)d_in[13];
    const float* fq_b2         = (const float*)d_in[14];
    const float* col_w1        = (const float*)d_in[15];
    const float* col_b1        = (const float*)d_in[16];
    const float* col_w2        = (const float*)d_in[17];
    const float* col_b2        = (const float*)d_in[18];
    const int*   tP            = (const int*)d_in[19];

    float* ws  = (float*)d_ws;
    float* out = (float*)d_out;
    const int N = in_sizes[0] / 3;

    hipLaunchKernelGGL(blob_sim_kernel, dim3(1), dim3(64), 0, stream,
                       initial_state, dyn_w1, dyn_b1, dyn_w2, dyn_b2,
                       coupling, damping, interaction, summ_w, summ_b,
                       fq_w1, fq_b1, fq_w2, fq_b2,
                       col_w1, col_b1, col_w2, col_b2, tP, ws);

    const int blocks = (N + 255) / 256;
    hipLaunchKernelGGL(field_kernel, dim3(blocks), dim3(256), 0, stream,
                       p, ws, out, N);
}

// Round 4
// 420.402 us; speedup vs baseline: 2.2028x; 2.0156x over previous
//
#include <hip/hip_runtime.h>
#include <math.h>

#define NB 20
#define SDIM 160   // 20*8
#define H1 64
#define TWO_PI_F 6.28318530717958647692f

// ws layout (floats)
#define WS_FQW   0      // [64][24]
#define WS_COLW  1536   // [64][24]
#define WS_FQB   3072   // [64] effective bias (b + summary part)
#define WS_COLB  3136   // [64]
#define WS_COLWD 3200   // [64] col_w1[j][56] (density weight)
#define WS_FQW2  3264   // [64]
#define WS_COLW2 3328   // [3][64]
#define WS_MISC  3520   // [0]=fq_b2, [1..3]=col_b2

__device__ __forceinline__ float fast_sigmoid(float x){ return 1.0f/(1.0f+__expf(-x)); }
__device__ __forceinline__ float fast_softplus(float x){
    return fmaxf(x, 0.0f) + __logf(1.0f + __expf(-fabsf(x)));
}
__device__ __forceinline__ float fast_rcp(float x){ return __builtin_amdgcn_rcpf(x); }
__device__ __forceinline__ float fast_rsq(float x){ return __builtin_amdgcn_rsqf(x); }
__device__ __forceinline__ float bperm(float v, int srcLane){
    return __int_as_float(__builtin_amdgcn_ds_bpermute(srcLane << 2, __float_as_int(v)));
}
__device__ __forceinline__ float rdlane(float v, int l){
    return __int_as_float(__builtin_amdgcn_readlane(__float_as_int(v), l));
}
__device__ __forceinline__ float getS(float s0, float s1, float s2, int f){
    return (f < 64) ? rdlane(s0, f) : (f < 128) ? rdlane(s1, f - 64) : rdlane(s2, f - 128);
}

// ---------------------------------------------------------------------------
// 4-wave blob simulation: per-step work split across 4 SIMDs, 2 barriers/step.
// Each wave holds a full replicated state in VGPRs (identical fp ops -> identical
// replicas). Waves 0-2 split phase-1 K=160; wave 3 does pair-split forces.
// Phase-2 K=64 splits 4 ways. Cross-wave partials via [idx][wave] LDS + b128.
// ---------------------------------------------------------------------------
__global__ __launch_bounds__(256, 1) void blob_sim_kernel(
    const float* __restrict__ initial_state,
    const float* __restrict__ dyn_w1, const float* __restrict__ dyn_b1,
    const float* __restrict__ dyn_w2, const float* __restrict__ dyn_b2,
    const float* __restrict__ couplingP, const float* __restrict__ dampingP,
    const float* __restrict__ interaction,
    const float* __restrict__ summ_w, const float* __restrict__ summ_b,
    const float* __restrict__ fq_w1, const float* __restrict__ fq_b1,
    const float* __restrict__ fq_w2, const float* __restrict__ fq_b2,
    const float* __restrict__ col_w1, const float* __restrict__ col_b1,
    const float* __restrict__ col_w2, const float* __restrict__ col_b2,
    const int* __restrict__ tP,
    float* __restrict__ ws)
{
    __shared__ float sW1T[160*64];   // staging [k][j]
    __shared__ float sW2T[64*128];   // staging [k][o], o<100 used, pad 0
    __shared__ float sP1L[64*4];     // phase-1 partials [j][wave]
    __shared__ float sDnP[128*4];    // phase-2 partials [o][wave]
    __shared__ float sFr[64];        // forces [b*3+c]
    __shared__ float sPosL[64];      // positions [b*3+c], maintained by wave 3
    __shared__ float sSum[32];

    const int tid  = threadIdx.x;
    const int wv   = tid >> 6;
    const int lane = tid & 63;

    // ---- one-time staging ----
    for (int idx = tid; idx < 160*64; idx += 256){
        int j = idx / 160, k = idx - j*160;
        sW1T[k*64 + j] = dyn_w1[idx];
    }
    for (int idx = tid; idx < 64*100; idx += 256){
        int k = idx / 100, o = idx - k*100;
        int ob = o / 5, oc = o - ob*5;
        sW2T[k*128 + o] = dyn_w2[(ob*8 + 3 + oc)*H1 + k];
    }
    for (int idx = tid; idx < 64*28; idx += 256){   // zero-pad o in [100,128)
        int k = idx / 28, o = 100 + (idx - (idx/28)*28);
        sW2T[k*128 + o] = 0.0f;
    }
    if (tid < 60) sPosL[tid] = initial_state[(tid/3)*8 + (tid - (tid/3)*3)];
    if (tid < 64) sP1L[tid*4 + 3] = 0.0f;   // wave-3 never writes phase-1 partials
    __syncthreads();

    // ---- per-wave register weights ----
    float w1s[54];
    if (wv < 3){
        const int kb = wv*53;
        #pragma unroll
        for (int t2 = 0; t2 < 54; ++t2) w1s[t2] = sW1T[(kb + t2)*64 + lane];
    }
    float w2a16[16], w2b16[16];
    {
        const int kb2 = wv*16;
        #pragma unroll
        for (int t2 = 0; t2 < 16; ++t2){
            w2a16[t2] = sW2T[(kb2 + t2)*128 + lane];
            w2b16[t2] = sW2T[(kb2 + t2)*128 + 64 + lane];
        }
    }

    // wave-3 force decomposition: lane = jg*20 + fi, jj range [jg*7, jg*7+7)
    const int fi  = lane % 20;
    const int jg  = lane / 20;
    const int jj0 = jg * 7;
    float rintw[7];
    #pragma unroll
    for (int u = 0; u < 7; ++u){
        int jj = jj0 + u;
        rintw[u] = (wv == 3 && lane < 60 && jj < NB) ? interaction[fi*NB + jj] : 0.0f;
    }

    // ---- replicated state ----
    float s0 = initial_state[lane];
    float s1 = initial_state[64 + lane];
    float s2 = (lane < 32) ? initial_state[128 + lane] : 0.0f;

    const float b1r = dyn_b1[lane];
    float b2ar, b2br;
    { int b = lane/5, c = lane - (lane/5)*5; b2ar = dyn_b2[b*8 + 3 + c]; }
    { int o2 = 64 + lane;
      if (o2 < 100){ int b = o2/5, c = o2 - (o2/5)*5; b2br = dyn_b2[b*8 + 3 + c]; }
      else b2br = 0.0f; }
    const float bA0 = (wv == 0) ? b2ar : 0.0f;   // fold bias into wave-0 partial
    const float bB0 = (wv == 0) ? b2br : 0.0f;

    const float coupling = couplingP[0];
    const float damping  = dampingP[0];
    const int tv = tP[0];
    int n_steps = (int)((double)tv / 0.01);   // replicates Python int(t/DT): 2 -> 199
    if (n_steps < 1) n_steps = 1;
    const float adt = (float)((double)tv / (double)n_steps);

    const int cc  = lane & 7;
    const int bb  = lane >> 3;
    const int cm3 = (cc >= 3) ? cc - 3 : 0;
    const int lp3 = (lane + 3 > 63) ? 63 : lane + 3;

    for (int step = 0; step < n_steps; ++step){
        float fx = 0.f, fy = 0.f, fz = 0.f;
        if (wv < 3){
            // ---- phase-1 partial: k-slice of h_pre = W1 @ s ----
            float aa[4] = {0.f, 0.f, 0.f, 0.f};
            if (wv == 0){
                #pragma unroll
                for (int t2 = 0; t2 < 53; ++t2)
                    aa[t2&3] = fmaf(rdlane(s0, t2), w1s[t2], aa[t2&3]);
            } else if (wv == 1){
                #pragma unroll
                for (int t2 = 0; t2 < 53; ++t2){
                    int k = 53 + t2;
                    float sv = (k < 64) ? rdlane(s0, k) : rdlane(s1, k - 64);
                    aa[t2&3] = fmaf(sv, w1s[t2], aa[t2&3]);
                }
            } else {
                #pragma unroll
                for (int t2 = 0; t2 < 54; ++t2){
                    int k = 106 + t2;
                    float sv = (k < 128) ? rdlane(s1, k - 64) : rdlane(s2, k - 128);
                    aa[t2&3] = fmaf(sv, w1s[t2], aa[t2&3]);
                }
            }
            sP1L[lane*4 + wv] = (aa[0] + aa[1]) + (aa[2] + aa[3]);
        } else {
            // ---- wave 3: forces, 7 pairs per lane ----
            float px = sPosL[fi*3+0], py = sPosL[fi*3+1], pz = sPosL[fi*3+2];
            #pragma unroll
            for (int u = 0; u < 7; ++u){
                int jj = jj0 + u;
                int js = (jj < NB) ? jj : 0;
                float dx = px - sPosL[js*3+0];
                float dy = py - sPosL[js*3+1];
                float dz = pz - sPosL[js*3+2];
                float e  = fmaf(dx,dx, fmaf(dy,dy, fmaf(dz,dz, 1e-6f)));
                float d  = e * fast_rsq(e);
                float mag = rintw[u] * fast_rcp(e + 1.0f);   // 0 when jj>=NB
                float w   = mag * fast_rcp(d + 1e-6f);
                fx = fmaf(dx, w, fx);
                fy = fmaf(dy, w, fy);
                fz = fmaf(dz, w, fz);
            }
            fx += bperm(fx, lane+20) + bperm(fx, lane+40);
            fy += bperm(fy, lane+20) + bperm(fy, lane+40);
            fz += bperm(fz, lane+20) + bperm(fz, lane+40);
        }

        __syncthreads();   // B1: phase-1 partials visible

        if (wv == 3 && lane < NB){   // post-B1: step-(n-1) readers are done
            sFr[lane*3+0] = fx; sFr[lane*3+1] = fy; sFr[lane*3+2] = fz;
        }

        // ---- h assemble (all waves, redundant) ----
        float4 pp = *(const float4*)&sP1L[lane*4];
        float hv = (pp.x + pp.y) + pp.z + b1r;
        hv = fminf(fmaxf(hv, -15.0f), 15.0f);
        float e2v = __expf(2.0f * hv);
        float hreg = (e2v - 1.0f) * fast_rcp(e2v + 1.0f);

        // ---- phase-2 partial: k-slice of dn = W2u @ h ----
        {
            float dA0=0.f, dA1=0.f, dB0=0.f, dB1=0.f;
            const int kb2 = wv*16;
            #pragma unroll
            for (int t2 = 0; t2 < 16; t2 += 2){
                float h0 = rdlane(hreg, kb2 + t2);
                float h1 = rdlane(hreg, kb2 + t2 + 1);
                dA0 = fmaf(h0, w2a16[t2],   dA0);
                dA1 = fmaf(h1, w2a16[t2+1], dA1);
                dB0 = fmaf(h0, w2b16[t2],   dB0);
                dB1 = fmaf(h1, w2b16[t2+1], dB1);
            }
            sDnP[lane*4 + wv]      = dA0 + dA1 + bA0;
            sDnP[(64+lane)*4 + wv] = dB0 + dB1 + bB0;
        }

        __syncthreads();   // B2: dn partials + forces visible

        // ---- update (replicated on every wave) ----
        {
            float v0 = bperm(s0, lp3);
            float v1 = bperm(s1, lp3);
            float v2 = bperm(s2, lp3);
            int o0 = bb*5 + cm3;
            int o1 = 40 + o0;
            int o2 = 80 + o0;          // may exceed 99 for lane>=32; in-bounds, unused
            float4 q0 = *(const float4*)&sDnP[o0*4];
            float4 q1 = *(const float4*)&sDnP[o1*4];
            float4 q2 = *(const float4*)&sDnP[o2*4];
            float dn0 = (q0.x + q0.y) + (q0.z + q0.w);
            float dn1 = (q1.x + q1.y) + (q1.z + q1.w);
            float dn2 = (q2.x + q2.y) + (q2.z + q2.w);
            float F0 = sFr[bb*3 + cm3];
            float F1 = sFr[(8+bb)*3 + cm3];
            float F2 = sFr[(lane < 32) ? (16+bb)*3 + cm3 : 0];

            float dv0 = (cc < 3) ? v0
                      : (cc < 6) ? fmaf(-damping, s0, fmaf(coupling, F0, dn0))
                      : (cc == 6) ? fmaf(-0.05f, s0 - 1.0f, dn0)
                                  : fmaf(-0.05f, s0 - 0.5f, dn0);
            float dv1 = (cc < 3) ? v1
                      : (cc < 6) ? fmaf(-damping, s1, fmaf(coupling, F1, dn1))
                      : (cc == 6) ? fmaf(-0.05f, s1 - 1.0f, dn1)
                                  : fmaf(-0.05f, s1 - 0.5f, dn1);
            float dv2 = (cc < 3) ? v2
                      : (cc < 6) ? fmaf(-damping, s2, fmaf(coupling, F2, dn2))
                      : (cc == 6) ? fmaf(-0.05f, s2 - 1.0f, dn2)
                                  : fmaf(-0.05f, s2 - 0.5f, dn2);

            s0 = fmaf(adt, dv0, s0);
            s1 = fmaf(adt, dv1, s1);
            s2 = fmaf(adt, dv2, s2);

            if (wv == 3 && cc < 3){   // only wave 3 maintains sPosL (it reads it)
                sPosL[bb*3 + cc]      = s0;
                sPosL[(8+bb)*3 + cc]  = s1;
                if (lane < 32) sPosL[(16+bb)*3 + cc] = s2;
            }
        }
    }

    if (wv != 0) return;   // tail on wave 0 only (no barriers below)

    // ---- summary = summ_w @ flat + summ_b ----
    {
        int sbase = (lane & 31) * SDIM;
        float sa = summ_b[lane & 31];
        #pragma unroll
        for (int k = 0; k < SDIM; ++k)
            sa = fmaf(getS(s0,s1,s2,k), summ_w[sbase + k], sa);
        if (lane < 32) sSum[lane] = sa;
    }

    // ---- pack field weights + fold summary into effective biases ----
    for (int idx = lane; idx < 64*24; idx += 64){
        int jj = idx / 24, k = idx - jj*24;
        ws[WS_FQW  + idx] = fq_w1[jj*56 + k];
        ws[WS_COLW + idx] = col_w1[jj*57 + k];
    }
    {
        float bq = fq_b1[lane], bc = col_b1[lane];
        #pragma unroll
        for (int m = 0; m < 32; ++m){
            bq = fmaf(sSum[m], fq_w1[lane*56 + 24 + m], bq);
            bc = fmaf(sSum[m], col_w1[lane*57 + 24 + m], bc);
        }
        ws[WS_FQB   + lane] = bq;
        ws[WS_COLB  + lane] = bc;
        ws[WS_COLWD + lane] = col_w1[lane*57 + 56];
        ws[WS_FQW2  + lane] = fq_w2[lane];
        ws[WS_COLW2 + lane]       = col_w2[lane];
        ws[WS_COLW2 + 64 + lane]  = col_w2[64 + lane];
        ws[WS_COLW2 + 128 + lane] = col_w2[128 + lane];
    }
    if (lane == 0){
        ws[WS_MISC + 0] = fq_b2[0];
        ws[WS_MISC + 1] = col_b2[0];
        ws[WS_MISC + 2] = col_b2[1];
        ws[WS_MISC + 3] = col_b2[2];
    }
}

__global__ __launch_bounds__(256) void field_kernel(
    const float* __restrict__ p,
    const float* __restrict__ ws,
    float* __restrict__ out, int N)
{
    const int i = blockIdx.x * 256 + threadIdx.x;
    if (i >= N) return;

    const float x0 = p[3*i], x1 = p[3*i+1], x2 = p[3*i+2];
    float penc[24];
    #pragma unroll
    for (int f = 0; f < 4; ++f){
        const float fr = (float)(1 << f);
        float s, c;
        __sincosf(TWO_PI_F * fr * x0, &s, &c); penc[f*6+0] = s; penc[f*6+3] = c;
        __sincosf(TWO_PI_F * fr * x1, &s, &c); penc[f*6+1] = s; penc[f*6+4] = c;
        __sincosf(TWO_PI_F * fr * x2, &s, &c); penc[f*6+2] = s; penc[f*6+5] = c;
    }

    const float* Wq  = ws + WS_FQW;
    const float* Wc  = ws + WS_COLW;
    const float* Bq  = ws + WS_FQB;
    const float* Bc  = ws + WS_COLB;
    const float* Wd  = ws + WS_COLWD;
    const float* W2q = ws + WS_FQW2;
    const float* W2c = ws + WS_COLW2;

    float dacc = ws[WS_MISC + 0];
    #pragma unroll 4
    for (int jj = 0; jj < 64; ++jj){
        float a = Bq[jj];
        #pragma unroll
        for (int k = 0; k < 24; ++k) a = fmaf(penc[k], Wq[jj*24 + k], a);
        a = fmaxf(a, 0.0f);
        dacc = fmaf(a, W2q[jj], dacc);
    }
    const float density = fast_softplus(dacc);

    float c0 = ws[WS_MISC + 1], c1 = ws[WS_MISC + 2], c2 = ws[WS_MISC + 3];
    #pragma unroll 4
    for (int jj = 0; jj < 64; ++jj){
        float a = Bc[jj];
        #pragma unroll
        for (int k = 0; k < 24; ++k) a = fmaf(penc[k], Wc[jj*24 + k], a);
        a = fmaf(density, Wd[jj], a);
        a = fmaxf(a, 0.0f);
        c0 = fmaf(a, W2c[jj],       c0);
        c1 = fmaf(a, W2c[64 + jj],  c1);
        c2 = fmaf(a, W2c[128 + jj], c2);
    }

    out[i] = density;
    float* oc = out + N;
    oc[3*i + 0] = fast_sigmoid(c0);
    oc[3*i + 1] = fast_sigmoid(c1);
    oc[3*i + 2] = fast_sigmoid(c2);
}

extern "C" void kernel_launch(void* const* d_in, const int* in_sizes, int n_in,
                              void* d_out, int out_size, void* d_ws, size_t ws_size,
                              hipStream_t stream)
{
    const float* p             = (const float*)d_in[0];
    const float* initial_state = (const float*)d_in[1];
    const float* dyn_w1        = (const float*)d_in[2];
    const float* dyn_b1        = (const float*)d_in[3];
    const float* dyn_w2        = (const float*)d_in[4];
    const float* dyn_b2        = (const float*)d_in[5];
    const float* coupling      = (const float*)d_in[6];
    const float* damping       = (const float*)d_in[7];
    const float* interaction   = (const float*)d_in[8];
    const float* summ_w        = (const float*)d_in[9];
    const float* summ_b        = (const float*)d_in[10];
    const float* fq_w1         = (const float*)d_in[11];
    const float* fq_b1         = (const float*)d_in[12];
    const float* fq_w2         = (const float*)d_in[13];
    const float* fq_b2         = (const float*)d_in[14];
    const float* col_w1        = (const float*)d_in[15];
    const float* col_b1        = (const float*)d_in[16];
    const float* col_w2        = (const float*)d_in[17];
    const float* col_b2        = (const float*)d_in[18];
    const int*   tP            = (const int*)d_in[19];

    float* ws  = (float*)d_ws;
    float* out = (float*)d_out;
    const int N = in_sizes[0] / 3;

    hipLaunchKernelGGL(blob_sim_kernel, dim3(1), dim3(256), 0, stream,
                       initial_state, dyn_w1, dyn_b1, dyn_w2, dyn_b2,
                       coupling, damping, interaction, summ_w, summ_b,
                       fq_w1, fq_b1, fq_w2, fq_b2,
                       col_w1, col_b1, col_w2, col_b2, tP, ws);

    const int blocks = (N + 255) / 256;
    hipLaunchKernelGGL(field_kernel, dim3(blocks), dim3(256), 0, stream,
                       p, ws, out, N);
}

// Round 5
// 366.196 us; speedup vs baseline: 2.5289x; 1.1480x over previous
//
#include <hip/hip_runtime.h>
#include <math.h>

#define NB 20
#define SDIM 160   // 20*8
#define H1 64
#define TWO_PI_F 6.28318530717958647692f

// ws layout (floats), all rows float4-aligned
#define WS_DROW  0      // 64 density rows x 28: [w0..w23, beff, w2q, pad, pad]
#define WS_CROW  1792   // 64 color rows  x 32: [w0..w23, beff, wd, w2c0, w2c1, w2c2, pad x3]
#define WS_MISC  3840   // [0]=fq_b2, [1..3]=col_b2

__device__ __forceinline__ float fast_sigmoid(float x){ return 1.0f/(1.0f+__expf(-x)); }
__device__ __forceinline__ float fast_softplus(float x){
    return fmaxf(x, 0.0f) + __logf(1.0f + __expf(-fabsf(x)));
}
__device__ __forceinline__ float fast_rcp(float x){ return __builtin_amdgcn_rcpf(x); }
__device__ __forceinline__ float fast_rsq(float x){ return __builtin_amdgcn_rsqf(x); }
__device__ __forceinline__ float bperm(float v, int srcLane){
    return __int_as_float(__builtin_amdgcn_ds_bpermute(srcLane << 2, __float_as_int(v)));
}
__device__ __forceinline__ float rdlane(float v, int l){
    return __int_as_float(__builtin_amdgcn_readlane(__float_as_int(v), l));
}
__device__ __forceinline__ float getS(float s0, float s1, float s2, int f){
    return (f < 64) ? rdlane(s0, f) : (f < 128) ? rdlane(s1, f - 64) : rdlane(s2, f - 128);
}

// 24-element dot with 4 independent partial chains (ILP)
__device__ __forceinline__ float dot24(const float* e,
    float4 w0, float4 w1, float4 w2, float4 w3, float4 w4, float4 w5, float b)
{
    float p0 = b, p1 = 0.f, p2 = 0.f, p3 = 0.f;
    p0 = fmaf(e[0],  w0.x, p0); p1 = fmaf(e[1],  w0.y, p1);
    p2 = fmaf(e[2],  w0.z, p2); p3 = fmaf(e[3],  w0.w, p3);
    p0 = fmaf(e[4],  w1.x, p0); p1 = fmaf(e[5],  w1.y, p1);
    p2 = fmaf(e[6],  w1.z, p2); p3 = fmaf(e[7],  w1.w, p3);
    p0 = fmaf(e[8],  w2.x, p0); p1 = fmaf(e[9],  w2.y, p1);
    p2 = fmaf(e[10], w2.z, p2); p3 = fmaf(e[11], w2.w, p3);
    p0 = fmaf(e[12], w3.x, p0); p1 = fmaf(e[13], w3.y, p1);
    p2 = fmaf(e[14], w3.z, p2); p3 = fmaf(e[15], w3.w, p3);
    p0 = fmaf(e[16], w4.x, p0); p1 = fmaf(e[17], w4.y, p1);
    p2 = fmaf(e[18], w4.z, p2); p3 = fmaf(e[19], w4.w, p3);
    p0 = fmaf(e[20], w5.x, p0); p1 = fmaf(e[21], w5.y, p1);
    p2 = fmaf(e[22], w5.z, p2); p3 = fmaf(e[23], w5.w, p3);
    return (p0 + p1) + (p2 + p3);
}

// ---------------------------------------------------------------------------
// 4-wave blob simulation (unchanged from round 4 except the ws packing tail).
// ---------------------------------------------------------------------------
__global__ __launch_bounds__(256, 1) void blob_sim_kernel(
    const float* __restrict__ initial_state,
    const float* __restrict__ dyn_w1, const float* __restrict__ dyn_b1,
    const float* __restrict__ dyn_w2, const float* __restrict__ dyn_b2,
    const float* __restrict__ couplingP, const float* __restrict__ dampingP,
    const float* __restrict__ interaction,
    const float* __restrict__ summ_w, const float* __restrict__ summ_b,
    const float* __restrict__ fq_w1, const float* __restrict__ fq_b1,
    const float* __restrict__ fq_w2, const float* __restrict__ fq_b2,
    const float* __restrict__ col_w1, const float* __restrict__ col_b1,
    const float* __restrict__ col_w2, const float* __restrict__ col_b2,
    const int* __restrict__ tP,
    float* __restrict__ ws)
{
    __shared__ float sW1T[160*64];   // staging [k][j]
    __shared__ float sW2T[64*128];   // staging [k][o], o<100 used, pad 0
    __shared__ float sP1L[64*4];     // phase-1 partials [j][wave]
    __shared__ float sDnP[128*4];    // phase-2 partials [o][wave]
    __shared__ float sFr[64];        // forces [b*3+c]
    __shared__ float sPosL[64];      // positions [b*3+c], maintained by wave 3
    __shared__ float sSum[32];

    const int tid  = threadIdx.x;
    const int wv   = tid >> 6;
    const int lane = tid & 63;

    // ---- one-time staging ----
    for (int idx = tid; idx < 160*64; idx += 256){
        int j = idx / 160, k = idx - j*160;
        sW1T[k*64 + j] = dyn_w1[idx];
    }
    for (int idx = tid; idx < 64*100; idx += 256){
        int k = idx / 100, o = idx - k*100;
        int ob = o / 5, oc = o - ob*5;
        sW2T[k*128 + o] = dyn_w2[(ob*8 + 3 + oc)*H1 + k];
    }
    for (int idx = tid; idx < 64*28; idx += 256){   // zero-pad o in [100,128)
        int k = idx / 28, o = 100 + (idx - (idx/28)*28);
        sW2T[k*128 + o] = 0.0f;
    }
    if (tid < 60) sPosL[tid] = initial_state[(tid/3)*8 + (tid - (tid/3)*3)];
    if (tid < 64) sP1L[tid*4 + 3] = 0.0f;   // wave-3 never writes phase-1 partials
    __syncthreads();

    // ---- per-wave register weights ----
    float w1s[54];
    if (wv < 3){
        const int kb = wv*53;
        #pragma unroll
        for (int t2 = 0; t2 < 54; ++t2) w1s[t2] = sW1T[(kb + t2)*64 + lane];
    }
    float w2a16[16], w2b16[16];
    {
        const int kb2 = wv*16;
        #pragma unroll
        for (int t2 = 0; t2 < 16; ++t2){
            w2a16[t2] = sW2T[(kb2 + t2)*128 + lane];
            w2b16[t2] = sW2T[(kb2 + t2)*128 + 64 + lane];
        }
    }

    // wave-3 force decomposition: lane = jg*20 + fi, jj range [jg*7, jg*7+7)
    const int fi  = lane % 20;
    const int jg  = lane / 20;
    const int jj0 = jg * 7;
    float rintw[7];
    #pragma unroll
    for (int u = 0; u < 7; ++u){
        int jj = jj0 + u;
        rintw[u] = (wv == 3 && lane < 60 && jj < NB) ? interaction[fi*NB + jj] : 0.0f;
    }

    // ---- replicated state ----
    float s0 = initial_state[lane];
    float s1 = initial_state[64 + lane];
    float s2 = (lane < 32) ? initial_state[128 + lane] : 0.0f;

    const float b1r = dyn_b1[lane];
    float b2ar, b2br;
    { int b = lane/5, c = lane - (lane/5)*5; b2ar = dyn_b2[b*8 + 3 + c]; }
    { int o2 = 64 + lane;
      if (o2 < 100){ int b = o2/5, c = o2 - (o2/5)*5; b2br = dyn_b2[b*8 + 3 + c]; }
      else b2br = 0.0f; }
    const float bA0 = (wv == 0) ? b2ar : 0.0f;
    const float bB0 = (wv == 0) ? b2br : 0.0f;

    const float coupling = couplingP[0];
    const float damping  = dampingP[0];
    const int tv = tP[0];
    int n_steps = (int)((double)tv / 0.01);   // replicates Python int(t/DT): 2 -> 199
    if (n_steps < 1) n_steps = 1;
    const float adt = (float)((double)tv / (double)n_steps);

    const int cc  = lane & 7;
    const int bb  = lane >> 3;
    const int cm3 = (cc >= 3) ? cc - 3 : 0;
    const int lp3 = (lane + 3 > 63) ? 63 : lane + 3;

    for (int step = 0; step < n_steps; ++step){
        float fx = 0.f, fy = 0.f, fz = 0.f;
        if (wv < 3){
            float aa[4] = {0.f, 0.f, 0.f, 0.f};
            if (wv == 0){
                #pragma unroll
                for (int t2 = 0; t2 < 53; ++t2)
                    aa[t2&3] = fmaf(rdlane(s0, t2), w1s[t2], aa[t2&3]);
            } else if (wv == 1){
                #pragma unroll
                for (int t2 = 0; t2 < 53; ++t2){
                    int k = 53 + t2;
                    float sv = (k < 64) ? rdlane(s0, k) : rdlane(s1, k - 64);
                    aa[t2&3] = fmaf(sv, w1s[t2], aa[t2&3]);
                }
            } else {
                #pragma unroll
                for (int t2 = 0; t2 < 54; ++t2){
                    int k = 106 + t2;
                    float sv = (k < 128) ? rdlane(s1, k - 64) : rdlane(s2, k - 128);
                    aa[t2&3] = fmaf(sv, w1s[t2], aa[t2&3]);
                }
            }
            sP1L[lane*4 + wv] = (aa[0] + aa[1]) + (aa[2] + aa[3]);
        } else {
            float px = sPosL[fi*3+0], py = sPosL[fi*3+1], pz = sPosL[fi*3+2];
            #pragma unroll
            for (int u = 0; u < 7; ++u){
                int jj = jj0 + u;
                int js = (jj < NB) ? jj : 0;
                float dx = px - sPosL[js*3+0];
                float dy = py - sPosL[js*3+1];
                float dz = pz - sPosL[js*3+2];
                float e  = fmaf(dx,dx, fmaf(dy,dy, fmaf(dz,dz, 1e-6f)));
                float d  = e * fast_rsq(e);
                float mag = rintw[u] * fast_rcp(e + 1.0f);
                float w   = mag * fast_rcp(d + 1e-6f);
                fx = fmaf(dx, w, fx);
                fy = fmaf(dy, w, fy);
                fz = fmaf(dz, w, fz);
            }
            fx += bperm(fx, lane+20) + bperm(fx, lane+40);
            fy += bperm(fy, lane+20) + bperm(fy, lane+40);
            fz += bperm(fz, lane+20) + bperm(fz, lane+40);
        }

        __syncthreads();   // B1: phase-1 partials visible

        if (wv == 3 && lane < NB){
            sFr[lane*3+0] = fx; sFr[lane*3+1] = fy; sFr[lane*3+2] = fz;
        }

        float4 pp = *(const float4*)&sP1L[lane*4];
        float hv = (pp.x + pp.y) + pp.z + b1r;
        hv = fminf(fmaxf(hv, -15.0f), 15.0f);
        float e2v = __expf(2.0f * hv);
        float hreg = (e2v - 1.0f) * fast_rcp(e2v + 1.0f);

        {
            float dA0=0.f, dA1=0.f, dB0=0.f, dB1=0.f;
            const int kb2 = wv*16;
            #pragma unroll
            for (int t2 = 0; t2 < 16; t2 += 2){
                float h0 = rdlane(hreg, kb2 + t2);
                float h1 = rdlane(hreg, kb2 + t2 + 1);
                dA0 = fmaf(h0, w2a16[t2],   dA0);
                dA1 = fmaf(h1, w2a16[t2+1], dA1);
                dB0 = fmaf(h0, w2b16[t2],   dB0);
                dB1 = fmaf(h1, w2b16[t2+1], dB1);
            }
            sDnP[lane*4 + wv]      = dA0 + dA1 + bA0;
            sDnP[(64+lane)*4 + wv] = dB0 + dB1 + bB0;
        }

        __syncthreads();   // B2: dn partials + forces visible

        {
            float v0 = bperm(s0, lp3);
            float v1 = bperm(s1, lp3);
            float v2 = bperm(s2, lp3);
            int o0 = bb*5 + cm3;
            int o1 = 40 + o0;
            int o2 = 80 + o0;
            float4 q0 = *(const float4*)&sDnP[o0*4];
            float4 q1 = *(const float4*)&sDnP[o1*4];
            float4 q2 = *(const float4*)&sDnP[o2*4];
            float dn0 = (q0.x + q0.y) + (q0.z + q0.w);
            float dn1 = (q1.x + q1.y) + (q1.z + q1.w);
            float dn2 = (q2.x + q2.y) + (q2.z + q2.w);
            float F0 = sFr[bb*3 + cm3];
            float F1 = sFr[(8+bb)*3 + cm3];
            float F2 = sFr[(lane < 32) ? (16+bb)*3 + cm3 : 0];

            float dv0 = (cc < 3) ? v0
                      : (cc < 6) ? fmaf(-damping, s0, fmaf(coupling, F0, dn0))
                      : (cc == 6) ? fmaf(-0.05f, s0 - 1.0f, dn0)
                                  : fmaf(-0.05f, s0 - 0.5f, dn0);
            float dv1 = (cc < 3) ? v1
                      : (cc < 6) ? fmaf(-damping, s1, fmaf(coupling, F1, dn1))
                      : (cc == 6) ? fmaf(-0.05f, s1 - 1.0f, dn1)
                                  : fmaf(-0.05f, s1 - 0.5f, dn1);
            float dv2 = (cc < 3) ? v2
                      : (cc < 6) ? fmaf(-damping, s2, fmaf(coupling, F2, dn2))
                      : (cc == 6) ? fmaf(-0.05f, s2 - 1.0f, dn2)
                                  : fmaf(-0.05f, s2 - 0.5f, dn2);

            s0 = fmaf(adt, dv0, s0);
            s1 = fmaf(adt, dv1, s1);
            s2 = fmaf(adt, dv2, s2);

            if (wv == 3 && cc < 3){
                sPosL[bb*3 + cc]      = s0;
                sPosL[(8+bb)*3 + cc]  = s1;
                if (lane < 32) sPosL[(16+bb)*3 + cc] = s2;
            }
        }
    }

    if (wv != 0) return;   // tail on wave 0 only (no barriers below)

    // ---- summary = summ_w @ flat + summ_b ----
    {
        int sbase = (lane & 31) * SDIM;
        float sa = summ_b[lane & 31];
        #pragma unroll
        for (int k = 0; k < SDIM; ++k)
            sa = fmaf(getS(s0,s1,s2,k), summ_w[sbase + k], sa);
        if (lane < 32) sSum[lane] = sa;
    }

    // ---- pack padded field-weight rows; fold summary into effective biases ----
    {
        const int j = lane;   // one row per lane
        // density row: 28 floats
        int base = WS_DROW + j*28;
        #pragma unroll
        for (int k = 0; k < 24; ++k) ws[base + k] = fq_w1[j*56 + k];
        float bq = fq_b1[j];
        #pragma unroll
        for (int m = 0; m < 32; ++m) bq = fmaf(sSum[m], fq_w1[j*56 + 24 + m], bq);
        ws[base + 24] = bq;
        ws[base + 25] = fq_w2[j];
        ws[base + 26] = 0.0f;
        ws[base + 27] = 0.0f;
        // color row: 32 floats
        base = WS_CROW + j*32;
        #pragma unroll
        for (int k = 0; k < 24; ++k) ws[base + k] = col_w1[j*57 + k];
        float bc = col_b1[j];
        #pragma unroll
        for (int m = 0; m < 32; ++m) bc = fmaf(sSum[m], col_w1[j*57 + 24 + m], bc);
        ws[base + 24] = bc;
        ws[base + 25] = col_w1[j*57 + 56];
        ws[base + 26] = col_w2[j];
        ws[base + 27] = col_w2[64 + j];
        ws[base + 28] = col_w2[128 + j];
        ws[base + 29] = 0.0f;
        ws[base + 30] = 0.0f;
        ws[base + 31] = 0.0f;
    }
    if (lane == 0){
        ws[WS_MISC + 0] = fq_b2[0];
        ws[WS_MISC + 1] = col_b2[0];
        ws[WS_MISC + 2] = col_b2[1];
        ws[WS_MISC + 3] = col_b2[2];
    }
}

// ---------------------------------------------------------------------------
// Field eval: 2 points per thread (interleaved by 256 for coalescing),
// padded float4 weight rows so each neuron is 7-8 dwordx4 loads reused by
// both points.
// ---------------------------------------------------------------------------
__global__ __launch_bounds__(256) void field_kernel(
    const float* __restrict__ p,
    const float* __restrict__ ws,
    float* __restrict__ out, int N)
{
    const int tid = threadIdx.x;
    const int iA  = blockIdx.x * 512 + tid;
    const int iB  = iA + 256;
    const int lA  = (iA < N) ? iA : 0;
    const int lB  = (iB < N) ? iB : 0;

    float eA[24], eB[24];
    {
        const float a0 = p[3*lA], a1 = p[3*lA+1], a2 = p[3*lA+2];
        const float b0 = p[3*lB], b1 = p[3*lB+1], b2 = p[3*lB+2];
        #pragma unroll
        for (int f = 0; f < 4; ++f){
            const float w = TWO_PI_F * (float)(1 << f);
            float s, c;
            __sincosf(w * a0, &s, &c); eA[f*6+0] = s; eA[f*6+3] = c;
            __sincosf(w * a1, &s, &c); eA[f*6+1] = s; eA[f*6+4] = c;
            __sincosf(w * a2, &s, &c); eA[f*6+2] = s; eA[f*6+5] = c;
            __sincosf(w * b0, &s, &c); eB[f*6+0] = s; eB[f*6+3] = c;
            __sincosf(w * b1, &s, &c); eB[f*6+1] = s; eB[f*6+4] = c;
            __sincosf(w * b2, &s, &c); eB[f*6+2] = s; eB[f*6+5] = c;
        }
    }

    const float m0  = ws[WS_MISC + 0];
    const float mc0 = ws[WS_MISC + 1];
    const float mc1 = ws[WS_MISC + 2];
    const float mc2 = ws[WS_MISC + 3];

    // ---- density MLP ----
    float dA = m0, dB = m0;
    {
        const float4* R = (const float4*)(ws + WS_DROW);
        #pragma unroll 2
        for (int jj = 0; jj < 64; ++jj){
            float4 w0 = R[jj*7+0], w1 = R[jj*7+1], w2 = R[jj*7+2];
            float4 w3 = R[jj*7+3], w4 = R[jj*7+4], w5 = R[jj*7+5];
            float4 w6 = R[jj*7+6];              // {beff, w2q, pad, pad}
            float aA = fmaxf(dot24(eA, w0,w1,w2,w3,w4,w5, w6.x), 0.0f);
            float aB = fmaxf(dot24(eB, w0,w1,w2,w3,w4,w5, w6.x), 0.0f);
            dA = fmaf(aA, w6.y, dA);
            dB = fmaf(aB, w6.y, dB);
        }
    }
    const float densA = fast_softplus(dA);
    const float densB = fast_softplus(dB);

    // ---- color MLP ----
    float cA0 = mc0, cA1 = mc1, cA2 = mc2;
    float cB0 = mc0, cB1 = mc1, cB2 = mc2;
    {
        const float4* R = (const float4*)(ws + WS_CROW);
        #pragma unroll 2
        for (int jj = 0; jj < 64; ++jj){
            float4 w0 = R[jj*8+0], w1 = R[jj*8+1], w2 = R[jj*8+2];
            float4 w3 = R[jj*8+3], w4 = R[jj*8+4], w5 = R[jj*8+5];
            float4 w6 = R[jj*8+6];              // {beff, wd, w2c0, w2c1}
            float4 w7 = R[jj*8+7];              // {w2c2, pad, pad, pad}
            float aA = dot24(eA, w0,w1,w2,w3,w4,w5, w6.x);
            float aB = dot24(eB, w0,w1,w2,w3,w4,w5, w6.x);
            aA = fmaxf(fmaf(densA, w6.y, aA), 0.0f);
            aB = fmaxf(fmaf(densB, w6.y, aB), 0.0f);
            cA0 = fmaf(aA, w6.z, cA0); cA1 = fmaf(aA, w6.w, cA1); cA2 = fmaf(aA, w7.x, cA2);
            cB0 = fmaf(aB, w6.z, cB0); cB1 = fmaf(aB, w6.w, cB1); cB2 = fmaf(aB, w7.x, cB2);
        }
    }

    float* oc = out + N;
    if (iA < N){
        out[iA] = densA;
        oc[3*iA + 0] = fast_sigmoid(cA0);
        oc[3*iA + 1] = fast_sigmoid(cA1);
        oc[3*iA + 2] = fast_sigmoid(cA2);
    }
    if (iB < N){
        out[iB] = densB;
        oc[3*iB + 0] = fast_sigmoid(cB0);
        oc[3*iB + 1] = fast_sigmoid(cB1);
        oc[3*iB + 2] = fast_sigmoid(cB2);
    }
}

extern "C" void kernel_launch(void* const* d_in, const int* in_sizes, int n_in,
                              void* d_out, int out_size, void* d_ws, size_t ws_size,
                              hipStream_t stream)
{
    const float* p             = (const float*)d_in[0];
    const float* initial_state = (const float*)d_in[1];
    const float* dyn_w1        = (const float*)d_in[2];
    const float* dyn_b1        = (const float*)d_in[3];
    const float* dyn_w2        = (const float*)d_in[4];
    const float* dyn_b2        = (const float*)d_in[5];
    const float* coupling      = (const float*)d_in[6];
    const float* damping       = (const float*)d_in[7];
    const float* interaction   = (const float*)d_in[8];
    const float* summ_w        = (const float*)d_in[9];
    const float* summ_b        = (const float*)d_in[10];
    const float* fq_w1         = (const float*)d_in[11];
    const float* fq_b1         = (const float*)d_in[12];
    const float* fq_w2         = (const float*)d_in[13];
    const float* fq_b2         = (const float*)d_in[14];
    const float* col_w1        = (const float*)d_in[15];
    const float* col_b1        = (const float*)d_in[16];
    const float* col_w2        = (const float*)d_in[17];
    const float* col_b2        = (const float*)d_in[18];
    const int*   tP            = (const int*)d_in[19];

    float* ws  = (float*)d_ws;
    float* out = (float*)d_out;
    const int N = in_sizes[0] / 3;

    hipLaunchKernelGGL(blob_sim_kernel, dim3(1), dim3(256), 0, stream,
                       initial_state, dyn_w1, dyn_b1, dyn_w2, dyn_b2,
                       coupling, damping, interaction, summ_w, summ_b,
                       fq_w1, fq_b1, fq_w2, fq_b2,
                       col_w1, col_b1, col_w2, col_b2, tP, ws);

    const int blocks = (N + 511) / 512;
    hipLaunchKernelGGL(field_kernel, dim3(blocks), dim3(256), 0, stream,
                       p, ws, out, N);
}